// Round 1
// baseline (1795.203 us; speedup 1.0000x reference)
//
#include <hip/hip_runtime.h>
#include <hip/hip_bf16.h>

#define NN 50000
#define EE 1600000
#define DD 512
#define HH 256
#define GG 16

// ---------------- degree count ----------------
__global__ void k_count(const int* __restrict__ ei, int* __restrict__ degc) {
    int e = blockIdx.x * 256 + threadIdx.x;
    if (e < EE) atomicAdd(&degc[ei[EE + e]], 1);
}

__global__ void k_dinv(const int* __restrict__ degc, float* __restrict__ dinv) {
    int i = blockIdx.x * 256 + threadIdx.x;
    if (i < NN) dinv[i] = rsqrtf((float)degc[i] + 1.0f);  // +1 self-loop
}

// ---------------- exclusive scan (single block) ----------------
__global__ __launch_bounds__(1024) void k_scan(const int* __restrict__ degc,
                                               int* __restrict__ rp, int* __restrict__ cur) {
    __shared__ int sm[1024];
    int t = threadIdx.x;
    int carry = 0;
    for (int base = 0; base < NN; base += 1024) {
        int v = (base + t < NN) ? degc[base + t] : 0;
        sm[t] = v;
        __syncthreads();
        for (int off = 1; off < 1024; off <<= 1) {
            int add = (t >= off) ? sm[t - off] : 0;
            __syncthreads();
            sm[t] += add;
            __syncthreads();
        }
        int excl = sm[t] - v;
        if (base + t < NN) { rp[base + t] = carry + excl; cur[base + t] = carry + excl; }
        int total = sm[1023];
        __syncthreads();
        carry += total;
    }
    if (t == 0) rp[NN] = carry;
}

// ---------------- CSR fill ----------------
__global__ void k_fill(const int* __restrict__ ei, int* __restrict__ cur, int* __restrict__ csrc) {
    int e = blockIdx.x * 256 + threadIdx.x;
    if (e < EE) {
        int s = ei[e], d = ei[EE + e];
        int pos = atomicAdd(&cur[d], 1);
        csrc[pos] = s;
    }
}

// ---------------- fp32 tiled GEMM: C[M x 256] = A[M x K] @ B[K x 256] ----------------
__global__ __launch_bounds__(256) void k_gemm(const float* __restrict__ A, const float* __restrict__ B,
                                              float* __restrict__ C, int M, int K) {
    __shared__ float As[16][65];
    __shared__ float Bs[16][65];
    const int tid = threadIdx.x;
    const int tx = tid & 15, ty = tid >> 4;
    const int row0 = blockIdx.x * 64, col0 = blockIdx.y * 64;
    const int ar = tid >> 2;         // 0..63
    const int ak = (tid & 3) * 4;    // 0,4,8,12
    const int bk = tid >> 4;         // 0..15
    const int bn = (tid & 15) * 4;   // 0..60
    float acc[4][4] = {};
    for (int kb = 0; kb < K; kb += 16) {
        float4 av = make_float4(0.f, 0.f, 0.f, 0.f);
        int arow = row0 + ar;
        if (arow < M) av = *(const float4*)(A + (size_t)arow * K + kb + ak);
        As[ak + 0][ar] = av.x; As[ak + 1][ar] = av.y; As[ak + 2][ar] = av.z; As[ak + 3][ar] = av.w;
        float4 bv = *(const float4*)(B + (size_t)(kb + bk) * 256 + col0 + bn);
        Bs[bk][bn + 0] = bv.x; Bs[bk][bn + 1] = bv.y; Bs[bk][bn + 2] = bv.z; Bs[bk][bn + 3] = bv.w;
        __syncthreads();
        #pragma unroll
        for (int kk = 0; kk < 16; ++kk) {
            float a0 = As[kk][ty * 4 + 0], a1 = As[kk][ty * 4 + 1];
            float a2 = As[kk][ty * 4 + 2], a3 = As[kk][ty * 4 + 3];
            float b0 = Bs[kk][tx * 4 + 0], b1 = Bs[kk][tx * 4 + 1];
            float b2 = Bs[kk][tx * 4 + 2], b3 = Bs[kk][tx * 4 + 3];
            acc[0][0] += a0 * b0; acc[0][1] += a0 * b1; acc[0][2] += a0 * b2; acc[0][3] += a0 * b3;
            acc[1][0] += a1 * b0; acc[1][1] += a1 * b1; acc[1][2] += a1 * b2; acc[1][3] += a1 * b3;
            acc[2][0] += a2 * b0; acc[2][1] += a2 * b1; acc[2][2] += a2 * b2; acc[2][3] += a2 * b3;
            acc[3][0] += a3 * b0; acc[3][1] += a3 * b1; acc[3][2] += a3 * b2; acc[3][3] += a3 * b3;
        }
        __syncthreads();
    }
    #pragma unroll
    for (int r = 0; r < 4; ++r) {
        int row = row0 + ty * 4 + r;
        if (row < M)
            *(float4*)(C + (size_t)row * 256 + col0 + tx * 4) =
                make_float4(acc[r][0], acc[r][1], acc[r][2], acc[r][3]);
    }
}

// ---------------- aggregation: out[i] = relu( sum_{j->i} w_ji m[j] + dinv_i^2 m[i] + b ) ----------------
__global__ __launch_bounds__(256) void k_agg(const float* __restrict__ m, const float* __restrict__ bias,
                                             const float* __restrict__ dinv, const int* __restrict__ rp,
                                             const int* __restrict__ cs, float* __restrict__ out,
                                             int do_relu) {
    int lane = threadIdx.x & 63;
    int node = blockIdx.x * 4 + (threadIdx.x >> 6);
    if (node >= NN) return;
    float di = dinv[node];
    float wi = di * di;
    float4 v = *(const float4*)(m + (size_t)node * 256 + lane * 4);
    float4 acc = make_float4(wi * v.x, wi * v.y, wi * v.z, wi * v.w);
    int p1 = rp[node + 1];
    for (int p = rp[node]; p < p1; ++p) {
        int s = cs[p];
        float w = dinv[s] * di;
        float4 u = *(const float4*)(m + (size_t)s * 256 + lane * 4);
        acc.x += w * u.x; acc.y += w * u.y; acc.z += w * u.z; acc.w += w * u.w;
    }
    float4 bb = *(const float4*)(bias + lane * 4);
    acc.x += bb.x; acc.y += bb.y; acc.z += bb.z; acc.w += bb.w;
    if (do_relu) {
        acc.x = fmaxf(acc.x, 0.f); acc.y = fmaxf(acc.y, 0.f);
        acc.z = fmaxf(acc.z, 0.f); acc.w = fmaxf(acc.w, 0.f);
    }
    *(float4*)(out + (size_t)node * 256 + lane * 4) = acc;
}

// ---------------- pooling (mean over graphs) ----------------
__global__ __launch_bounds__(256) void k_pool(const float* __restrict__ h, const int* __restrict__ batch,
                                              float* __restrict__ pooled, float* __restrict__ cnts) {
    __shared__ float pl[GG * 256];
    __shared__ float cl[GG];
    int t = threadIdx.x;
    for (int i = t; i < GG * 256; i += 256) pl[i] = 0.f;
    if (t < GG) cl[t] = 0.f;
    __syncthreads();
    int chunk = (NN + gridDim.x - 1) / gridDim.x;
    int i0 = blockIdx.x * chunk;
    int i1 = i0 + chunk; if (i1 > NN) i1 = NN;
    for (int i = i0; i < i1; ++i) {
        int g = batch[i];
        pl[g * 256 + t] += h[(size_t)i * 256 + t];
        if (t == 0) cl[g] += 1.f;
    }
    __syncthreads();
    for (int i = t; i < GG * 256; i += 256)
        if (pl[i] != 0.f) atomicAdd(&pooled[i], pl[i]);
    if (t < GG && cl[t] != 0.f) atomicAdd(&cnts[t], cl[t]);
}

// ---------------- head: (pooled/cnt) @ Wf + bf -> @ Wp + bp -> sigmoid ----------------
__global__ __launch_bounds__(1024) void k_head(const float* __restrict__ pooled, const float* __restrict__ cnts,
                                               const float* __restrict__ Wf, const float* __restrict__ bf,
                                               const float* __restrict__ Wp, const float* __restrict__ bp,
                                               float* __restrict__ out) {
    __shared__ float z[GG][64];
    int t = threadIdx.x;
    int g = t >> 6, j = t & 63;
    float inv = 1.f / fmaxf(cnts[g], 1.f);
    float acc = 0.f;
    for (int k = 0; k < 256; ++k) acc += pooled[g * 256 + k] * Wf[k * 64 + j];
    z[g][j] = acc * inv + bf[j];
    __syncthreads();
    if (t < GG) {
        float o = 0.f;
        for (int j2 = 0; j2 < 64; ++j2) o += z[t][j2] * Wp[j2];
        o += bp[0];
        out[t] = 1.f / (1.f + expf(-o));
    }
}

extern "C" void kernel_launch(void* const* d_in, const int* in_sizes, int n_in,
                              void* d_out, int out_size, void* d_ws, size_t ws_size,
                              hipStream_t stream) {
    const float* x   = (const float*)d_in[0];
    const int*   ei  = (const int*)d_in[1];
    const int*   bat = (const int*)d_in[2];
    const float* W1  = (const float*)d_in[3];
    const float* b1  = (const float*)d_in[4];
    const float* W2  = (const float*)d_in[5];
    const float* b2  = (const float*)d_in[6];
    const float* W3  = (const float*)d_in[7];
    const float* b3  = (const float*)d_in[8];
    const float* Wf  = (const float*)d_in[9];
    const float* bf  = (const float*)d_in[10];
    const float* Wp  = (const float*)d_in[11];
    const float* bp  = (const float*)d_in[12];
    float* out = (float*)d_out;

    char* w = (char*)d_ws;
    float* bufA   = (float*)w;                 w += (size_t)NN * HH * 4;   // m
    float* bufB   = (float*)w;                 w += (size_t)NN * HH * 4;   // h
    float* dinv   = (float*)w;                 w += (size_t)NN * 4;
    int*   degc   = (int*)w;                   w += (size_t)NN * 4;
    int*   rp     = (int*)w;                   w += (size_t)(NN + 4) * 4;
    int*   cur    = (int*)w;                   w += (size_t)NN * 4;
    int*   csrc   = (int*)w;                   w += (size_t)EE * 4;
    float* pooled = (float*)w;                 w += (size_t)GG * HH * 4;
    float* cnts   = (float*)w;                 w += (size_t)GG * 4;

    hipMemsetAsync(degc, 0, (size_t)NN * 4, stream);
    hipMemsetAsync(pooled, 0, (size_t)(GG * HH + GG) * 4, stream);

    k_count<<<(EE + 255) / 256, 256, 0, stream>>>(ei, degc);
    k_dinv<<<(NN + 255) / 256, 256, 0, stream>>>(degc, dinv);
    k_scan<<<1, 1024, 0, stream>>>(degc, rp, cur);
    k_fill<<<(EE + 255) / 256, 256, 0, stream>>>(ei, cur, csrc);

    dim3 g1((NN + 63) / 64, 4);
    // layer 1
    k_gemm<<<g1, 256, 0, stream>>>(x, W1, bufA, NN, DD);
    k_agg<<<(NN + 3) / 4, 256, 0, stream>>>(bufA, b1, dinv, rp, csrc, bufB, 1);
    // layer 2
    k_gemm<<<g1, 256, 0, stream>>>(bufB, W2, bufA, NN, HH);
    k_agg<<<(NN + 3) / 4, 256, 0, stream>>>(bufA, b2, dinv, rp, csrc, bufB, 1);
    // layer 3
    k_gemm<<<g1, 256, 0, stream>>>(bufB, W3, bufA, NN, HH);
    k_agg<<<(NN + 3) / 4, 256, 0, stream>>>(bufA, b3, dinv, rp, csrc, bufB, 0);

    k_pool<<<256, 256, 0, stream>>>(bufB, bat, pooled, cnts);
    k_head<<<1, 1024, 0, stream>>>(pooled, cnts, Wf, bf, Wp, bp, out);
}

// Round 2
// 1225.449 us; speedup vs baseline: 1.4649x; 1.4649x over previous
//
#include <hip/hip_runtime.h>
#include <hip/hip_bf16.h>

#define NN 50000
#define EE 1600000
#define DD 512
#define HH 256
#define GG 16

typedef __attribute__((ext_vector_type(8))) short bf16x8;
typedef __attribute__((ext_vector_type(4))) float f32x4;

__device__ __forceinline__ unsigned short f2b(float f) {
    union { float f; unsigned int u; } v; v.f = f;
    unsigned int r = v.u + 0x7fffu + ((v.u >> 16) & 1u);
    return (unsigned short)(r >> 16);
}

// ---------------- degree count ----------------
__global__ void k_count(const int* __restrict__ ei, int* __restrict__ degc) {
    int e = blockIdx.x * 256 + threadIdx.x;
    if (e < EE) atomicAdd(&degc[ei[EE + e]], 1);
}

__global__ void k_dinv(const int* __restrict__ degc, float* __restrict__ dinv) {
    int i = blockIdx.x * 256 + threadIdx.x;
    if (i < NN) dinv[i] = rsqrtf((float)degc[i] + 1.0f);  // +1 self-loop
}

// ---------------- multi-block exclusive scan ----------------
__global__ __launch_bounds__(1024) void k_scan1(const int* __restrict__ degc,
                                                int* __restrict__ rp, int* __restrict__ bsum) {
    __shared__ int sm[1024];
    int t = threadIdx.x;
    int i = blockIdx.x * 1024 + t;
    int v = (i < NN) ? degc[i] : 0;
    sm[t] = v;
    __syncthreads();
    for (int off = 1; off < 1024; off <<= 1) {
        int add = (t >= off) ? sm[t - off] : 0;
        __syncthreads();
        sm[t] += add;
        __syncthreads();
    }
    if (i < NN) rp[i] = sm[t] - v;            // local exclusive
    if (t == 1023) bsum[blockIdx.x] = sm[1023];
}

__global__ void k_scan2(const int* __restrict__ bsum, int* __restrict__ boff,
                        int nb, int* __restrict__ rp_last) {
    if (threadIdx.x == 0 && blockIdx.x == 0) {
        int acc = 0;
        for (int b = 0; b < nb; ++b) { boff[b] = acc; acc += bsum[b]; }
        rp_last[0] = acc;                      // rp[NN]
    }
}

__global__ void k_scan3(int* __restrict__ rp, const int* __restrict__ boff, int* __restrict__ cur) {
    int i = blockIdx.x * 256 + threadIdx.x;
    if (i < NN) {
        int v = rp[i] + boff[i >> 10];
        rp[i] = v; cur[i] = v;
    }
}

// ---------------- CSR fill ----------------
__global__ void k_fill(const int* __restrict__ ei, int* __restrict__ cur, int* __restrict__ csrc) {
    int e = blockIdx.x * 256 + threadIdx.x;
    if (e < EE) {
        int s = ei[e], d = ei[EE + e];
        int pos = atomicAdd(&cur[d], 1);
        csrc[pos] = s;
    }
}

// ---------------- conversions ----------------
__global__ void k_cvt_x(const float* __restrict__ x, unsigned short* __restrict__ xb, int n4) {
    int i = blockIdx.x * 256 + threadIdx.x;
    if (i < n4) {
        float4 v = *(const float4*)(x + (size_t)i * 4);
        ushort4 o;
        o.x = f2b(v.x); o.y = f2b(v.y); o.z = f2b(v.z); o.w = f2b(v.w);
        *(ushort4*)(xb + (size_t)i * 4) = o;
    }
}

// W [K,H] fp32 -> Wt [H,K] bf16 (Wt[n*K+k] = W[k*H+n])
__global__ void k_cvt_w(const float* __restrict__ W, unsigned short* __restrict__ Wt, int K) {
    int t = blockIdx.x * 256 + threadIdx.x;
    if (t < K * HH) {
        int k = t >> 8, n = t & 255;
        Wt[(size_t)n * K + k] = f2b(W[t]);
    }
}

// ---------------- bf16 MFMA GEMM: C[M x 256] = A[M x K](bf16) @ Bt[256 x K](bf16)^T ----------------
__global__ __launch_bounds__(256) void k_gemm_bf16(const unsigned short* __restrict__ A,
                                                   const unsigned short* __restrict__ Bt,
                                                   float* __restrict__ C, int M, int K) {
    __shared__ unsigned short As[128 * 32];   // [row][k], row stride 32 elts (64 B)
    __shared__ unsigned short Bs[128 * 32];   // [col][k]
    const int tid  = threadIdx.x;
    const int wave = tid >> 6;
    const int lane = tid & 63;
    const int row0 = blockIdx.x * 128;
    const int col0 = blockIdx.y * 128;
    const int wr = wave & 1;                  // wave row-block (64 rows)
    const int wc = wave >> 1;                 // wave col-block (64 cols)
    const int l15 = lane & 15;
    const int quad = lane >> 4;

    // staging map: thread t covers 16 B at chunk-LDS offset t*16 -> row=t/4, kbyte=(t%4)*16
    const int sr = tid >> 2;
    const int sk = (tid & 3) * 8;             // element offset in k

    int ar0 = row0 + sr;        if (ar0 >= M) ar0 = M - 1;
    int ar1 = row0 + 64 + sr;   if (ar1 >= M) ar1 = M - 1;
    const int bc0 = col0 + sr;
    const int bc1 = col0 + 64 + sr;

    f32x4 acc[4][4];
    #pragma unroll
    for (int i = 0; i < 4; ++i)
        #pragma unroll
        for (int j = 0; j < 4; ++j)
            acc[i][j] = (f32x4){0.f, 0.f, 0.f, 0.f};

    for (int kb = 0; kb < K; kb += 32) {
        const unsigned short* ga0 = A + (size_t)ar0 * K + kb + sk;
        const unsigned short* ga1 = A + (size_t)ar1 * K + kb + sk;
        const unsigned short* gb0 = Bt + (size_t)bc0 * K + kb + sk;
        const unsigned short* gb1 = Bt + (size_t)bc1 * K + kb + sk;
        __builtin_amdgcn_global_load_lds((const __attribute__((address_space(1))) void*)ga0,
            (__attribute__((address_space(3))) void*)&As[wave * 512], 16, 0, 0);
        __builtin_amdgcn_global_load_lds((const __attribute__((address_space(1))) void*)ga1,
            (__attribute__((address_space(3))) void*)&As[2048 + wave * 512], 16, 0, 0);
        __builtin_amdgcn_global_load_lds((const __attribute__((address_space(1))) void*)gb0,
            (__attribute__((address_space(3))) void*)&Bs[wave * 512], 16, 0, 0);
        __builtin_amdgcn_global_load_lds((const __attribute__((address_space(1))) void*)gb1,
            (__attribute__((address_space(3))) void*)&Bs[2048 + wave * 512], 16, 0, 0);
        __syncthreads();

        bf16x8 af[4], bfr[4];
        #pragma unroll
        for (int mi = 0; mi < 4; ++mi)
            af[mi] = *(const bf16x8*)&As[(wr * 64 + mi * 16 + l15) * 32 + quad * 8];
        #pragma unroll
        for (int ni = 0; ni < 4; ++ni)
            bfr[ni] = *(const bf16x8*)&Bs[(wc * 64 + ni * 16 + l15) * 32 + quad * 8];
        #pragma unroll
        for (int mi = 0; mi < 4; ++mi)
            #pragma unroll
            for (int ni = 0; ni < 4; ++ni)
                acc[mi][ni] = __builtin_amdgcn_mfma_f32_16x16x32_bf16(af[mi], bfr[ni], acc[mi][ni], 0, 0, 0);
        __syncthreads();
    }

    // epilogue: C/D layout col=lane&15, row=quad*4+r
    #pragma unroll
    for (int mi = 0; mi < 4; ++mi) {
        #pragma unroll
        for (int ni = 0; ni < 4; ++ni) {
            int gcol = col0 + wc * 64 + ni * 16 + l15;
            #pragma unroll
            for (int r = 0; r < 4; ++r) {
                int grow = row0 + wr * 64 + mi * 16 + quad * 4 + r;
                if (grow < M) C[(size_t)grow * 256 + gcol] = acc[mi][ni][r];
            }
        }
    }
}

// ---------------- aggregation: out[i] = act( sum_{j->i} w_ji m[j] + dinv_i^2 m[i] + b ) ----------------
__global__ __launch_bounds__(256) void k_agg(const float* __restrict__ m, const float* __restrict__ bias,
                                             const float* __restrict__ dinv, const int* __restrict__ rp,
                                             const int* __restrict__ cs,
                                             unsigned short* __restrict__ outb,   // bf16 out (if wb)
                                             float* __restrict__ outf,            // fp32 out (if !wb)
                                             int do_relu, int wb) {
    int lane = threadIdx.x & 63;
    int node = blockIdx.x * 4 + (threadIdx.x >> 6);
    if (node >= NN) return;
    float di = dinv[node];
    float wi = di * di;
    float4 v = *(const float4*)(m + (size_t)node * 256 + lane * 4);
    float4 acc = make_float4(wi * v.x, wi * v.y, wi * v.z, wi * v.w);
    int p1 = rp[node + 1];
    for (int p = rp[node]; p < p1; ++p) {
        int s = cs[p];
        float w = dinv[s] * di;
        float4 u = *(const float4*)(m + (size_t)s * 256 + lane * 4);
        acc.x += w * u.x; acc.y += w * u.y; acc.z += w * u.z; acc.w += w * u.w;
    }
    const float4 bb = *(const float4*)(bias + lane * 4);
    acc.x += bb.x; acc.y += bb.y; acc.z += bb.z; acc.w += bb.w;
    if (do_relu) {
        acc.x = fmaxf(acc.x, 0.f); acc.y = fmaxf(acc.y, 0.f);
        acc.z = fmaxf(acc.z, 0.f); acc.w = fmaxf(acc.w, 0.f);
    }
    if (wb) {
        ushort4 o;
        o.x = f2b(acc.x); o.y = f2b(acc.y); o.z = f2b(acc.z); o.w = f2b(acc.w);
        *(ushort4*)(outb + (size_t)node * 256 + lane * 4) = o;
    } else {
        *(float4*)(outf + (size_t)node * 256 + lane * 4) = acc;
    }
}

// ---------------- pooling (mean over graphs) ----------------
__global__ __launch_bounds__(256) void k_pool(const float* __restrict__ h, const int* __restrict__ batch,
                                              float* __restrict__ pooled, float* __restrict__ cnts) {
    __shared__ float pl[GG * 256];
    __shared__ float cl[GG];
    int t = threadIdx.x;
    for (int i = t; i < GG * 256; i += 256) pl[i] = 0.f;
    if (t < GG) cl[t] = 0.f;
    __syncthreads();
    int chunk = (NN + gridDim.x - 1) / gridDim.x;
    int i0 = blockIdx.x * chunk;
    int i1 = i0 + chunk; if (i1 > NN) i1 = NN;
    for (int i = i0; i < i1; ++i) {
        int g = batch[i];
        pl[g * 256 + t] += h[(size_t)i * 256 + t];
        if (t == 0) cl[g] += 1.f;
    }
    __syncthreads();
    for (int i = t; i < GG * 256; i += 256)
        if (pl[i] != 0.f) atomicAdd(&pooled[i], pl[i]);
    if (t < GG && cl[t] != 0.f) atomicAdd(&cnts[t], cl[t]);
}

// ---------------- head ----------------
__global__ __launch_bounds__(1024) void k_head(const float* __restrict__ pooled, const float* __restrict__ cnts,
                                               const float* __restrict__ Wf, const float* __restrict__ bf,
                                               const float* __restrict__ Wp, const float* __restrict__ bp,
                                               float* __restrict__ out) {
    __shared__ float z[GG][64];
    int t = threadIdx.x;
    int g = t >> 6, j = t & 63;
    float inv = 1.f / fmaxf(cnts[g], 1.f);
    float acc = 0.f;
    for (int k = 0; k < 256; ++k) acc += pooled[g * 256 + k] * Wf[k * 64 + j];
    z[g][j] = acc * inv + bf[j];
    __syncthreads();
    if (t < GG) {
        float o = 0.f;
        for (int j2 = 0; j2 < 64; ++j2) o += z[t][j2] * Wp[j2];
        o += bp[0];
        out[t] = 1.f / (1.f + expf(-o));
    }
}

extern "C" void kernel_launch(void* const* d_in, const int* in_sizes, int n_in,
                              void* d_out, int out_size, void* d_ws, size_t ws_size,
                              hipStream_t stream) {
    const float* x   = (const float*)d_in[0];
    const int*   ei  = (const int*)d_in[1];
    const int*   bat = (const int*)d_in[2];
    const float* W1  = (const float*)d_in[3];
    const float* b1  = (const float*)d_in[4];
    const float* W2  = (const float*)d_in[5];
    const float* b2  = (const float*)d_in[6];
    const float* W3  = (const float*)d_in[7];
    const float* b3  = (const float*)d_in[8];
    const float* Wf  = (const float*)d_in[9];
    const float* bf  = (const float*)d_in[10];
    const float* Wp  = (const float*)d_in[11];
    const float* bp  = (const float*)d_in[12];
    float* out = (float*)d_out;

    char* w = (char*)d_ws;
    unsigned short* xb  = (unsigned short*)w;  w += (size_t)NN * DD * 2;   // 51.2 MB (bf16 x; reused as hf fp32)
    float*          hf  = (float*)xb;                                      // alias: layer-3 fp32 output
    float*          mf  = (float*)w;           w += (size_t)NN * HH * 4;   // 51.2 MB fp32 gemm out
    unsigned short* hb  = (unsigned short*)w;  w += (size_t)NN * HH * 2;   // 25.6 MB bf16 h
    unsigned short* W1t = (unsigned short*)w;  w += (size_t)DD * HH * 2;
    unsigned short* W2t = (unsigned short*)w;  w += (size_t)HH * HH * 2;
    unsigned short* W3t = (unsigned short*)w;  w += (size_t)HH * HH * 2;
    float* dinv   = (float*)w;                 w += (size_t)NN * 4;
    int*   degc   = (int*)w;                   w += (size_t)NN * 4;
    int*   rp     = (int*)w;                   w += (size_t)(NN + 4) * 4;
    int*   cur    = (int*)w;                   w += (size_t)NN * 4;
    int*   csrc   = (int*)w;                   w += (size_t)EE * 4;
    int*   bsum   = (int*)w;                   w += 64 * 4;
    int*   boff   = (int*)w;                   w += 64 * 4;
    float* pooled = (float*)w;                 w += (size_t)GG * HH * 4;
    float* cnts   = (float*)w;                 w += (size_t)GG * 4;

    hipMemsetAsync(degc, 0, (size_t)NN * 4, stream);
    hipMemsetAsync(pooled, 0, (size_t)(GG * HH + GG) * 4, stream);

    // graph structure
    k_count<<<(EE + 255) / 256, 256, 0, stream>>>(ei, degc);
    k_dinv<<<(NN + 255) / 256, 256, 0, stream>>>(degc, dinv);
    int nb = (NN + 1023) / 1024;
    k_scan1<<<nb, 1024, 0, stream>>>(degc, rp, bsum);
    k_scan2<<<1, 64, 0, stream>>>(bsum, boff, nb, rp + NN);
    k_scan3<<<(NN + 255) / 256, 256, 0, stream>>>(rp, boff, cur);
    k_fill<<<(EE + 255) / 256, 256, 0, stream>>>(ei, cur, csrc);

    // conversions
    k_cvt_x<<<(NN * DD / 4 + 255) / 256, 256, 0, stream>>>(x, xb, NN * DD / 4);
    k_cvt_w<<<(DD * HH + 255) / 256, 256, 0, stream>>>(W1, W1t, DD);
    k_cvt_w<<<(HH * HH + 255) / 256, 256, 0, stream>>>(W2, W2t, HH);
    k_cvt_w<<<(HH * HH + 255) / 256, 256, 0, stream>>>(W3, W3t, HH);

    dim3 gg((NN + 127) / 128, 2);
    // layer 1
    k_gemm_bf16<<<gg, 256, 0, stream>>>(xb, W1t, mf, NN, DD);
    k_agg<<<(NN + 3) / 4, 256, 0, stream>>>(mf, b1, dinv, rp, csrc, hb, nullptr, 1, 1);
    // layer 2
    k_gemm_bf16<<<gg, 256, 0, stream>>>(hb, W2t, mf, NN, HH);
    k_agg<<<(NN + 3) / 4, 256, 0, stream>>>(mf, b2, dinv, rp, csrc, hb, nullptr, 1, 1);
    // layer 3
    k_gemm_bf16<<<gg, 256, 0, stream>>>(hb, W3t, mf, NN, HH);
    k_agg<<<(NN + 3) / 4, 256, 0, stream>>>(mf, b3, dinv, rp, csrc, nullptr, hf, 0, 0);

    k_pool<<<256, 256, 0, stream>>>(hf, bat, pooled, cnts);
    k_head<<<1, 1024, 0, stream>>>(pooled, cnts, Wf, bf, Wp, bp, out);
}

// Round 3
// 1216.027 us; speedup vs baseline: 1.4763x; 1.0077x over previous
//
#include <hip/hip_runtime.h>
#include <hip/hip_bf16.h>

#define NN 50000
#define EE 1600000
#define DD 512
#define HH 256
#define GG 16

typedef __attribute__((ext_vector_type(8))) short bf16x8;
typedef __attribute__((ext_vector_type(4))) float f32x4;

__device__ __forceinline__ unsigned short f2b(float f) {
    union { float f; unsigned int u; } v; v.f = f;
    unsigned int r = v.u + 0x7fffu + ((v.u >> 16) & 1u);
    return (unsigned short)(r >> 16);
}
__device__ __forceinline__ float b2f_lo(unsigned int u) {
    union { unsigned int i; float f; } v; v.i = u << 16; return v.f;
}
__device__ __forceinline__ float b2f_hi(unsigned int u) {
    union { unsigned int i; float f; } v; v.i = u & 0xffff0000u; return v.f;
}

// ---------------- degree count ----------------
__global__ void k_count(const int* __restrict__ ei, int* __restrict__ degc) {
    int e = blockIdx.x * 256 + threadIdx.x;
    if (e < EE) atomicAdd(&degc[ei[EE + e]], 1);
}

// ---------------- multi-block exclusive scan ----------------
__global__ __launch_bounds__(1024) void k_scan1(const int* __restrict__ degc,
                                                int* __restrict__ rp, int* __restrict__ bsum) {
    __shared__ int sm[1024];
    int t = threadIdx.x;
    int i = blockIdx.x * 1024 + t;
    int v = (i < NN) ? degc[i] : 0;
    sm[t] = v;
    __syncthreads();
    for (int off = 1; off < 1024; off <<= 1) {
        int add = (t >= off) ? sm[t - off] : 0;
        __syncthreads();
        sm[t] += add;
        __syncthreads();
    }
    if (i < NN) rp[i] = sm[t] - v;            // local exclusive
    if (t == 1023) bsum[blockIdx.x] = sm[1023];
}

__global__ void k_scan2(const int* __restrict__ bsum, int* __restrict__ boff,
                        int nb, int* __restrict__ rp_last) {
    if (threadIdx.x == 0 && blockIdx.x == 0) {
        int acc = 0;
        for (int b = 0; b < nb; ++b) { boff[b] = acc; acc += bsum[b]; }
        rp_last[0] = acc;                      // rp[NN]
    }
}

// finalize rp/cur + compute dinv
__global__ void k_scan3(int* __restrict__ rp, const int* __restrict__ boff, int* __restrict__ cur,
                        const int* __restrict__ degc, float* __restrict__ dinv) {
    int i = blockIdx.x * 256 + threadIdx.x;
    if (i < NN) {
        int v = rp[i] + boff[i >> 10];
        rp[i] = v; cur[i] = v;
        dinv[i] = rsqrtf((float)degc[i] + 1.0f);  // +1 self-loop
    }
}

// ---------------- CSR fill ----------------
__global__ void k_fill(const int* __restrict__ ei, int* __restrict__ cur, int* __restrict__ csrc) {
    int e = blockIdx.x * 256 + threadIdx.x;
    if (e < EE) {
        int s = ei[e], d = ei[EE + e];
        int pos = atomicAdd(&cur[d], 1);
        csrc[pos] = s;
    }
}

// ---------------- conversions ----------------
__global__ void k_cvt_x(const float* __restrict__ x, unsigned short* __restrict__ xb, int n4) {
    int i = blockIdx.x * 256 + threadIdx.x;
    if (i < n4) {
        float4 v = *(const float4*)(x + (size_t)i * 4);
        ushort4 o;
        o.x = f2b(v.x); o.y = f2b(v.y); o.z = f2b(v.z); o.w = f2b(v.w);
        *(ushort4*)(xb + (size_t)i * 4) = o;
    }
}

// all three weights: W [K,256] fp32 -> Wt [256,K] bf16
__global__ void k_cvt_wall(const float* __restrict__ W1, const float* __restrict__ W2,
                           const float* __restrict__ W3, unsigned short* __restrict__ W1t,
                           unsigned short* __restrict__ W2t, unsigned short* __restrict__ W3t) {
    int t = blockIdx.x * 256 + threadIdx.x;
    if (t < 131072) {                 // 512*256
        int k = t >> 8, n = t & 255;
        W1t[(size_t)n * 512 + k] = f2b(W1[t]);
    } else if (t < 196608) {          // + 256*256
        int u = t - 131072; int k = u >> 8, n = u & 255;
        W2t[(size_t)n * 256 + k] = f2b(W2[u]);
    } else if (t < 262144) {
        int u = t - 196608; int k = u >> 8, n = u & 255;
        W3t[(size_t)n * 256 + k] = f2b(W3[u]);
    }
}

// ---------------- bf16 MFMA GEMM: C[M x 256](bf16) = A[M x K](bf16) @ Bt[256 x K](bf16)^T ----------------
__global__ __launch_bounds__(256) void k_gemm_bf16(const unsigned short* __restrict__ A,
                                                   const unsigned short* __restrict__ Bt,
                                                   unsigned short* __restrict__ C, int M, int K) {
    __shared__ unsigned short As[128 * 32];   // [row][k], row stride 32 elts (64 B)
    __shared__ unsigned short Bs[128 * 32];   // [col][k]
    const int tid  = threadIdx.x;
    const int wave = tid >> 6;
    const int lane = tid & 63;
    const int row0 = blockIdx.x * 128;
    const int col0 = blockIdx.y * 128;
    const int wr = wave & 1;
    const int wc = wave >> 1;
    const int l15 = lane & 15;
    const int quad = lane >> 4;

    const int sr = tid >> 2;
    const int sk = (tid & 3) * 8;

    int ar0 = row0 + sr;        if (ar0 >= M) ar0 = M - 1;
    int ar1 = row0 + 64 + sr;   if (ar1 >= M) ar1 = M - 1;
    const int bc0 = col0 + sr;
    const int bc1 = col0 + 64 + sr;

    f32x4 acc[4][4];
    #pragma unroll
    for (int i = 0; i < 4; ++i)
        #pragma unroll
        for (int j = 0; j < 4; ++j)
            acc[i][j] = (f32x4){0.f, 0.f, 0.f, 0.f};

    for (int kb = 0; kb < K; kb += 32) {
        const unsigned short* ga0 = A + (size_t)ar0 * K + kb + sk;
        const unsigned short* ga1 = A + (size_t)ar1 * K + kb + sk;
        const unsigned short* gb0 = Bt + (size_t)bc0 * K + kb + sk;
        const unsigned short* gb1 = Bt + (size_t)bc1 * K + kb + sk;
        __builtin_amdgcn_global_load_lds((const __attribute__((address_space(1))) void*)ga0,
            (__attribute__((address_space(3))) void*)&As[wave * 512], 16, 0, 0);
        __builtin_amdgcn_global_load_lds((const __attribute__((address_space(1))) void*)ga1,
            (__attribute__((address_space(3))) void*)&As[2048 + wave * 512], 16, 0, 0);
        __builtin_amdgcn_global_load_lds((const __attribute__((address_space(1))) void*)gb0,
            (__attribute__((address_space(3))) void*)&Bs[wave * 512], 16, 0, 0);
        __builtin_amdgcn_global_load_lds((const __attribute__((address_space(1))) void*)gb1,
            (__attribute__((address_space(3))) void*)&Bs[2048 + wave * 512], 16, 0, 0);
        __syncthreads();

        bf16x8 af[4], bfr[4];
        #pragma unroll
        for (int mi = 0; mi < 4; ++mi)
            af[mi] = *(const bf16x8*)&As[(wr * 64 + mi * 16 + l15) * 32 + quad * 8];
        #pragma unroll
        for (int ni = 0; ni < 4; ++ni)
            bfr[ni] = *(const bf16x8*)&Bs[(wc * 64 + ni * 16 + l15) * 32 + quad * 8];
        #pragma unroll
        for (int mi = 0; mi < 4; ++mi)
            #pragma unroll
            for (int ni = 0; ni < 4; ++ni)
                acc[mi][ni] = __builtin_amdgcn_mfma_f32_16x16x32_bf16(af[mi], bfr[ni], acc[mi][ni], 0, 0, 0);
        __syncthreads();
    }

    #pragma unroll
    for (int mi = 0; mi < 4; ++mi) {
        #pragma unroll
        for (int ni = 0; ni < 4; ++ni) {
            int gcol = col0 + wc * 64 + ni * 16 + l15;
            #pragma unroll
            for (int r = 0; r < 4; ++r) {
                int grow = row0 + wr * 64 + mi * 16 + quad * 4 + r;
                if (grow < M) C[(size_t)grow * 256 + gcol] = f2b(acc[mi][ni][r]);
            }
        }
    }
}

// ---------------- aggregation over bf16 rows ----------------
// out[i] = act( sum_{j->i} w_ji m[j] + dinv_i^2 m[i] + b ),  m bf16, accum fp32
__global__ __launch_bounds__(256) void k_agg(const unsigned short* __restrict__ m,
                                             const float* __restrict__ bias,
                                             const float* __restrict__ dinv, const int* __restrict__ rp,
                                             const int* __restrict__ cs,
                                             unsigned short* __restrict__ outb,
                                             float* __restrict__ outf,
                                             int do_relu, int wb) {
    int lane = threadIdx.x & 63;
    int node = blockIdx.x * 4 + (threadIdx.x >> 6);
    if (node >= NN) return;
    float di = dinv[node];
    float wi = di * di;
    uint2 v = *(const uint2*)(m + (size_t)node * 256 + lane * 4);
    float4 acc;
    acc.x = wi * b2f_lo(v.x); acc.y = wi * b2f_hi(v.x);
    acc.z = wi * b2f_lo(v.y); acc.w = wi * b2f_hi(v.y);
    int p1 = rp[node + 1];
    for (int p = rp[node]; p < p1; ++p) {
        int s = cs[p];
        float w = dinv[s] * di;
        uint2 u = *(const uint2*)(m + (size_t)s * 256 + lane * 4);
        acc.x += w * b2f_lo(u.x); acc.y += w * b2f_hi(u.x);
        acc.z += w * b2f_lo(u.y); acc.w += w * b2f_hi(u.y);
    }
    const float4 bb = *(const float4*)(bias + lane * 4);
    acc.x += bb.x; acc.y += bb.y; acc.z += bb.z; acc.w += bb.w;
    if (do_relu) {
        acc.x = fmaxf(acc.x, 0.f); acc.y = fmaxf(acc.y, 0.f);
        acc.z = fmaxf(acc.z, 0.f); acc.w = fmaxf(acc.w, 0.f);
    }
    if (wb) {
        ushort4 o;
        o.x = f2b(acc.x); o.y = f2b(acc.y); o.z = f2b(acc.z); o.w = f2b(acc.w);
        *(ushort4*)(outb + (size_t)node * 256 + lane * 4) = o;
    } else {
        *(float4*)(outf + (size_t)node * 256 + lane * 4) = acc;
    }
}

// ---------------- pooling (mean over graphs) ----------------
__global__ __launch_bounds__(256) void k_pool(const float* __restrict__ h, const int* __restrict__ batch,
                                              float* __restrict__ pooled, float* __restrict__ cnts) {
    __shared__ float pl[GG * 256];
    __shared__ float cl[GG];
    int t = threadIdx.x;
    for (int i = t; i < GG * 256; i += 256) pl[i] = 0.f;
    if (t < GG) cl[t] = 0.f;
    __syncthreads();
    int chunk = (NN + gridDim.x - 1) / gridDim.x;
    int i0 = blockIdx.x * chunk;
    int i1 = i0 + chunk; if (i1 > NN) i1 = NN;
    for (int i = i0; i < i1; ++i) {
        int g = batch[i];
        pl[g * 256 + t] += h[(size_t)i * 256 + t];
        if (t == 0) cl[g] += 1.f;
    }
    __syncthreads();
    for (int i = t; i < GG * 256; i += 256)
        if (pl[i] != 0.f) atomicAdd(&pooled[i], pl[i]);
    if (t < GG && cl[t] != 0.f) atomicAdd(&cnts[t], cl[t]);
}

// ---------------- head ----------------
__global__ __launch_bounds__(1024) void k_head(const float* __restrict__ pooled, const float* __restrict__ cnts,
                                               const float* __restrict__ Wf, const float* __restrict__ bf,
                                               const float* __restrict__ Wp, const float* __restrict__ bp,
                                               float* __restrict__ out) {
    __shared__ float z[GG][64];
    int t = threadIdx.x;
    int g = t >> 6, j = t & 63;
    float inv = 1.f / fmaxf(cnts[g], 1.f);
    float acc = 0.f;
    for (int k = 0; k < 256; ++k) acc += pooled[g * 256 + k] * Wf[k * 64 + j];
    z[g][j] = acc * inv + bf[j];
    __syncthreads();
    if (t < GG) {
        float o = 0.f;
        for (int j2 = 0; j2 < 64; ++j2) o += z[t][j2] * Wp[j2];
        o += bp[0];
        out[t] = 1.f / (1.f + expf(-o));
    }
}

extern "C" void kernel_launch(void* const* d_in, const int* in_sizes, int n_in,
                              void* d_out, int out_size, void* d_ws, size_t ws_size,
                              hipStream_t stream) {
    const float* x   = (const float*)d_in[0];
    const int*   ei  = (const int*)d_in[1];
    const int*   bat = (const int*)d_in[2];
    const float* W1  = (const float*)d_in[3];
    const float* b1  = (const float*)d_in[4];
    const float* W2  = (const float*)d_in[5];
    const float* b2  = (const float*)d_in[6];
    const float* W3  = (const float*)d_in[7];
    const float* b3  = (const float*)d_in[8];
    const float* Wf  = (const float*)d_in[9];
    const float* bf  = (const float*)d_in[10];
    const float* Wp  = (const float*)d_in[11];
    const float* bp  = (const float*)d_in[12];
    float* out = (float*)d_out;

    char* w = (char*)d_ws;
    unsigned short* xb  = (unsigned short*)w;  w += (size_t)NN * DD * 2;   // bf16 x; reused as hf fp32
    float*          hf  = (float*)xb;                                      // alias: layer-3 agg fp32 output
    unsigned short* mb  = (unsigned short*)w;  w += (size_t)NN * HH * 2;   // bf16 gemm out
    unsigned short* hb  = (unsigned short*)w;  w += (size_t)NN * HH * 2;   // bf16 h
    unsigned short* W1t = (unsigned short*)w;  w += (size_t)DD * HH * 2;
    unsigned short* W2t = (unsigned short*)w;  w += (size_t)HH * HH * 2;
    unsigned short* W3t = (unsigned short*)w;  w += (size_t)HH * HH * 2;
    float* dinv   = (float*)w;                 w += (size_t)NN * 4;
    int*   degc   = (int*)w;                   w += (size_t)NN * 4;
    int*   rp     = (int*)w;                   w += (size_t)(NN + 4) * 4;
    int*   cur    = (int*)w;                   w += (size_t)NN * 4;
    int*   csrc   = (int*)w;                   w += (size_t)EE * 4;
    int*   bsum   = (int*)w;                   w += 64 * 4;
    int*   boff   = (int*)w;                   w += 64 * 4;
    float* pooled = (float*)w;                 w += (size_t)GG * HH * 4;
    float* cnts   = (float*)w;                 w += (size_t)GG * 4;

    hipMemsetAsync(degc, 0, (size_t)NN * 4, stream);
    hipMemsetAsync(pooled, 0, (size_t)(GG * HH + GG) * 4, stream);

    // graph structure
    k_count<<<(EE + 255) / 256, 256, 0, stream>>>(ei, degc);
    int nb = (NN + 1023) / 1024;
    k_scan1<<<nb, 1024, 0, stream>>>(degc, rp, bsum);
    k_scan2<<<1, 64, 0, stream>>>(bsum, boff, nb, rp + NN);
    k_scan3<<<(NN + 255) / 256, 256, 0, stream>>>(rp, boff, cur, degc, dinv);
    k_fill<<<(EE + 255) / 256, 256, 0, stream>>>(ei, cur, csrc);

    // conversions
    k_cvt_x<<<(NN * DD / 4 + 255) / 256, 256, 0, stream>>>(x, xb, NN * DD / 4);
    k_cvt_wall<<<(262144 + 255) / 256, 256, 0, stream>>>(W1, W2, W3, W1t, W2t, W3t);

    dim3 gg((NN + 127) / 128, 2);
    // layer 1
    k_gemm_bf16<<<gg, 256, 0, stream>>>(xb, W1t, mb, NN, DD);
    k_agg<<<(NN + 3) / 4, 256, 0, stream>>>(mb, b1, dinv, rp, csrc, hb, nullptr, 1, 1);
    // layer 2
    k_gemm_bf16<<<gg, 256, 0, stream>>>(hb, W2t, mb, NN, HH);
    k_agg<<<(NN + 3) / 4, 256, 0, stream>>>(mb, b2, dinv, rp, csrc, hb, nullptr, 1, 1);
    // layer 3
    k_gemm_bf16<<<gg, 256, 0, stream>>>(hb, W3t, mb, NN, HH);
    k_agg<<<(NN + 3) / 4, 256, 0, stream>>>(mb, b3, dinv, rp, csrc, nullptr, hf, 0, 0);

    k_pool<<<256, 256, 0, stream>>>(hf, bat, pooled, cnts);
    k_head<<<1, 1024, 0, stream>>>(pooled, cnts, Wf, bf, Wp, bp, out);
}

// Round 4
// 826.206 us; speedup vs baseline: 2.1728x; 1.4718x over previous
//
#include <hip/hip_runtime.h>
#include <hip/hip_bf16.h>

#define NN 50000
#define EE 1600000
#define DD 512
#define HH 256
#define GG 16

typedef __attribute__((ext_vector_type(8))) short bf16x8;
typedef __attribute__((ext_vector_type(4))) float f32x4;

__device__ __forceinline__ unsigned short f2b(float f) {
    union { float f; unsigned int u; } v; v.f = f;
    unsigned int r = v.u + 0x7fffu + ((v.u >> 16) & 1u);
    return (unsigned short)(r >> 16);
}
__device__ __forceinline__ float b2f_lo(unsigned int u) {
    union { unsigned int i; float f; } v; v.i = u << 16; return v.f;
}
__device__ __forceinline__ float b2f_hi(unsigned int u) {
    union { unsigned int i; float f; } v; v.i = u & 0xffff0000u; return v.f;
}
__device__ __forceinline__ float b2f(unsigned short s) {
    union { unsigned int i; float f; } v; v.i = ((unsigned int)s) << 16; return v.f;
}

// ---------------- degree count ----------------
__global__ void k_count(const int* __restrict__ ei, int* __restrict__ degc) {
    int e = blockIdx.x * 256 + threadIdx.x;
    if (e < EE) atomicAdd(&degc[ei[EE + e]], 1);
}

// ---------------- multi-block exclusive scan ----------------
__global__ __launch_bounds__(1024) void k_scan1(const int* __restrict__ degc,
                                                int* __restrict__ rp, int* __restrict__ bsum) {
    __shared__ int sm[1024];
    int t = threadIdx.x;
    int i = blockIdx.x * 1024 + t;
    int v = (i < NN) ? degc[i] : 0;
    sm[t] = v;
    __syncthreads();
    for (int off = 1; off < 1024; off <<= 1) {
        int add = (t >= off) ? sm[t - off] : 0;
        __syncthreads();
        sm[t] += add;
        __syncthreads();
    }
    if (i < NN) rp[i] = sm[t] - v;
    if (t == 1023) bsum[blockIdx.x] = sm[1023];
}

__global__ void k_scan2(const int* __restrict__ bsum, int* __restrict__ boff,
                        int nb, int* __restrict__ rp_last) {
    if (threadIdx.x == 0 && blockIdx.x == 0) {
        int acc = 0;
        for (int b = 0; b < nb; ++b) { boff[b] = acc; acc += bsum[b]; }
        rp_last[0] = acc;
    }
}

__global__ void k_scan3(int* __restrict__ rp, const int* __restrict__ boff, int* __restrict__ cur,
                        const int* __restrict__ degc, float* __restrict__ dinv) {
    int i = blockIdx.x * 256 + threadIdx.x;
    if (i < NN) {
        int v = rp[i] + boff[i >> 10];
        rp[i] = v; cur[i] = v;
        dinv[i] = rsqrtf((float)degc[i] + 1.0f);
    }
}

// ---------------- CSR fill with fused edge records {src, dinv[src]} ----------------
__global__ void k_fill(const int* __restrict__ ei, int* __restrict__ cur,
                       const float* __restrict__ dinv, uint2* __restrict__ er) {
    int e = blockIdx.x * 256 + threadIdx.x;
    if (e < EE) {
        int s = ei[e], d = ei[EE + e];
        int pos = atomicAdd(&cur[d], 1);
        uint2 rec;
        rec.x = (unsigned int)s;
        rec.y = __float_as_uint(dinv[s]);
        er[pos] = rec;
    }
}

// ---------------- conversions ----------------
__global__ void k_cvt_x(const float* __restrict__ x, unsigned short* __restrict__ xb, int n4) {
    int i = blockIdx.x * 256 + threadIdx.x;
    if (i < n4) {
        float4 v = *(const float4*)(x + (size_t)i * 4);
        ushort4 o;
        o.x = f2b(v.x); o.y = f2b(v.y); o.z = f2b(v.z); o.w = f2b(v.w);
        *(ushort4*)(xb + (size_t)i * 4) = o;
    }
}

__global__ void k_cvt_wall(const float* __restrict__ W1, const float* __restrict__ W2,
                           const float* __restrict__ W3, unsigned short* __restrict__ W1t,
                           unsigned short* __restrict__ W2t, unsigned short* __restrict__ W3t) {
    int t = blockIdx.x * 256 + threadIdx.x;
    if (t < 131072) {
        int k = t >> 8, n = t & 255;
        W1t[(size_t)n * 512 + k] = f2b(W1[t]);
    } else if (t < 196608) {
        int u = t - 131072; int k = u >> 8, n = u & 255;
        W2t[(size_t)n * 256 + k] = f2b(W2[u]);
    } else if (t < 262144) {
        int u = t - 196608; int k = u >> 8, n = u & 255;
        W3t[(size_t)n * 256 + k] = f2b(W3[u]);
    }
}

// ---------------- bf16 MFMA GEMM ----------------
__global__ __launch_bounds__(256) void k_gemm_bf16(const unsigned short* __restrict__ A,
                                                   const unsigned short* __restrict__ Bt,
                                                   unsigned short* __restrict__ C, int M, int K) {
    __shared__ unsigned short As[128 * 32];
    __shared__ unsigned short Bs[128 * 32];
    const int tid  = threadIdx.x;
    const int wave = tid >> 6;
    const int lane = tid & 63;
    const int row0 = blockIdx.x * 128;
    const int col0 = blockIdx.y * 128;
    const int wr = wave & 1;
    const int wc = wave >> 1;
    const int l15 = lane & 15;
    const int quad = lane >> 4;

    const int sr = tid >> 2;
    const int sk = (tid & 3) * 8;

    int ar0 = row0 + sr;        if (ar0 >= M) ar0 = M - 1;
    int ar1 = row0 + 64 + sr;   if (ar1 >= M) ar1 = M - 1;
    const int bc0 = col0 + sr;
    const int bc1 = col0 + 64 + sr;

    f32x4 acc[4][4];
    #pragma unroll
    for (int i = 0; i < 4; ++i)
        #pragma unroll
        for (int j = 0; j < 4; ++j)
            acc[i][j] = (f32x4){0.f, 0.f, 0.f, 0.f};

    for (int kb = 0; kb < K; kb += 32) {
        const unsigned short* ga0 = A + (size_t)ar0 * K + kb + sk;
        const unsigned short* ga1 = A + (size_t)ar1 * K + kb + sk;
        const unsigned short* gb0 = Bt + (size_t)bc0 * K + kb + sk;
        const unsigned short* gb1 = Bt + (size_t)bc1 * K + kb + sk;
        __builtin_amdgcn_global_load_lds((const __attribute__((address_space(1))) void*)ga0,
            (__attribute__((address_space(3))) void*)&As[wave * 512], 16, 0, 0);
        __builtin_amdgcn_global_load_lds((const __attribute__((address_space(1))) void*)ga1,
            (__attribute__((address_space(3))) void*)&As[2048 + wave * 512], 16, 0, 0);
        __builtin_amdgcn_global_load_lds((const __attribute__((address_space(1))) void*)gb0,
            (__attribute__((address_space(3))) void*)&Bs[wave * 512], 16, 0, 0);
        __builtin_amdgcn_global_load_lds((const __attribute__((address_space(1))) void*)gb1,
            (__attribute__((address_space(3))) void*)&Bs[2048 + wave * 512], 16, 0, 0);
        __syncthreads();

        bf16x8 af[4], bfr[4];
        #pragma unroll
        for (int mi = 0; mi < 4; ++mi)
            af[mi] = *(const bf16x8*)&As[(wr * 64 + mi * 16 + l15) * 32 + quad * 8];
        #pragma unroll
        for (int ni = 0; ni < 4; ++ni)
            bfr[ni] = *(const bf16x8*)&Bs[(wc * 64 + ni * 16 + l15) * 32 + quad * 8];
        #pragma unroll
        for (int mi = 0; mi < 4; ++mi)
            #pragma unroll
            for (int ni = 0; ni < 4; ++ni)
                acc[mi][ni] = __builtin_amdgcn_mfma_f32_16x16x32_bf16(af[mi], bfr[ni], acc[mi][ni], 0, 0, 0);
        __syncthreads();
    }

    #pragma unroll
    for (int mi = 0; mi < 4; ++mi) {
        #pragma unroll
        for (int ni = 0; ni < 4; ++ni) {
            int gcol = col0 + wc * 64 + ni * 16 + l15;
            #pragma unroll
            for (int r = 0; r < 4; ++r) {
                int grow = row0 + wr * 64 + mi * 16 + quad * 4 + r;
                if (grow < M) C[(size_t)grow * 256 + gcol] = f2b(acc[mi][ni][r]);
            }
        }
    }
}

// ---------------- aggregation: out[i] = act( di*(sum_j dinv_j*m_j + di*m_i) + b ) ----------------
__global__ __launch_bounds__(256) void k_agg(const unsigned short* __restrict__ m,
                                             const float* __restrict__ bias,
                                             const float* __restrict__ dinv, const int* __restrict__ rp,
                                             const uint2* __restrict__ er,
                                             unsigned short* __restrict__ outb,
                                             int do_relu) {
    int lane = threadIdx.x & 63;
    int node = blockIdx.x * 4 + (threadIdx.x >> 6);
    if (node >= NN) return;
    float di = dinv[node];
    const unsigned short* mrow = m + lane * 4;
    uint2 v = *(const uint2*)(mrow + (size_t)node * 256);
    float4 acc;
    acc.x = di * b2f_lo(v.x); acc.y = di * b2f_hi(v.x);
    acc.z = di * b2f_lo(v.y); acc.w = di * b2f_hi(v.y);
    int p0 = rp[node], p1 = rp[node + 1];
    int p = p0;
    // 4-deep pipelined gathers: 4 independent row loads in flight per wave
    for (; p + 4 <= p1; p += 4) {
        uint2 e0 = er[p], e1 = er[p + 1], e2 = er[p + 2], e3 = er[p + 3];
        uint2 u0 = *(const uint2*)(mrow + (size_t)e0.x * 256);
        uint2 u1 = *(const uint2*)(mrow + (size_t)e1.x * 256);
        uint2 u2 = *(const uint2*)(mrow + (size_t)e2.x * 256);
        uint2 u3 = *(const uint2*)(mrow + (size_t)e3.x * 256);
        float w0 = __uint_as_float(e0.y), w1 = __uint_as_float(e1.y);
        float w2 = __uint_as_float(e2.y), w3 = __uint_as_float(e3.y);
        acc.x += w0 * b2f_lo(u0.x) + w1 * b2f_lo(u1.x) + w2 * b2f_lo(u2.x) + w3 * b2f_lo(u3.x);
        acc.y += w0 * b2f_hi(u0.x) + w1 * b2f_hi(u1.x) + w2 * b2f_hi(u2.x) + w3 * b2f_hi(u3.x);
        acc.z += w0 * b2f_lo(u0.y) + w1 * b2f_lo(u1.y) + w2 * b2f_lo(u2.y) + w3 * b2f_lo(u3.y);
        acc.w += w0 * b2f_hi(u0.y) + w1 * b2f_hi(u1.y) + w2 * b2f_hi(u2.y) + w3 * b2f_hi(u3.y);
    }
    for (; p < p1; ++p) {
        uint2 e = er[p];
        uint2 u = *(const uint2*)(mrow + (size_t)e.x * 256);
        float w = __uint_as_float(e.y);
        acc.x += w * b2f_lo(u.x); acc.y += w * b2f_hi(u.x);
        acc.z += w * b2f_lo(u.y); acc.w += w * b2f_hi(u.y);
    }
    const float4 bb = *(const float4*)(bias + lane * 4);
    acc.x = acc.x * di + bb.x; acc.y = acc.y * di + bb.y;
    acc.z = acc.z * di + bb.z; acc.w = acc.w * di + bb.w;
    if (do_relu) {
        acc.x = fmaxf(acc.x, 0.f); acc.y = fmaxf(acc.y, 0.f);
        acc.z = fmaxf(acc.z, 0.f); acc.w = fmaxf(acc.w, 0.f);
    }
    ushort4 o;
    o.x = f2b(acc.x); o.y = f2b(acc.y); o.z = f2b(acc.z); o.w = f2b(acc.w);
    *(ushort4*)(outb + (size_t)node * 256 + lane * 4) = o;
}

// ---------------- pooling (mean over graphs), bf16 input ----------------
__global__ __launch_bounds__(256) void k_pool(const unsigned short* __restrict__ h,
                                              const int* __restrict__ batch,
                                              float* __restrict__ pooled, float* __restrict__ cnts) {
    __shared__ float pl[GG * 256];
    __shared__ float cl[GG];
    int t = threadIdx.x;
    for (int i = t; i < GG * 256; i += 256) pl[i] = 0.f;
    if (t < GG) cl[t] = 0.f;
    __syncthreads();
    int chunk = (NN + gridDim.x - 1) / gridDim.x;
    int i0 = blockIdx.x * chunk;
    int i1 = i0 + chunk; if (i1 > NN) i1 = NN;
    for (int i = i0; i < i1; ++i) {
        int g = batch[i];
        pl[g * 256 + t] += b2f(h[(size_t)i * 256 + t]);
        if (t == 0) cl[g] += 1.f;
    }
    __syncthreads();
    for (int i = t; i < GG * 256; i += 256)
        if (pl[i] != 0.f) atomicAdd(&pooled[i], pl[i]);
    if (t < GG && cl[t] != 0.f) atomicAdd(&cnts[t], cl[t]);
}

// ---------------- head ----------------
__global__ __launch_bounds__(1024) void k_head(const float* __restrict__ pooled, const float* __restrict__ cnts,
                                               const float* __restrict__ Wf, const float* __restrict__ bf,
                                               const float* __restrict__ Wp, const float* __restrict__ bp,
                                               float* __restrict__ out) {
    __shared__ float z[GG][64];
    int t = threadIdx.x;
    int g = t >> 6, j = t & 63;
    float inv = 1.f / fmaxf(cnts[g], 1.f);
    float acc = 0.f;
    for (int k = 0; k < 256; ++k) acc += pooled[g * 256 + k] * Wf[k * 64 + j];
    z[g][j] = acc * inv + bf[j];
    __syncthreads();
    if (t < GG) {
        float o = 0.f;
        for (int j2 = 0; j2 < 64; ++j2) o += z[t][j2] * Wp[j2];
        o += bp[0];
        out[t] = 1.f / (1.f + expf(-o));
    }
}

extern "C" void kernel_launch(void* const* d_in, const int* in_sizes, int n_in,
                              void* d_out, int out_size, void* d_ws, size_t ws_size,
                              hipStream_t stream) {
    const float* x   = (const float*)d_in[0];
    const int*   ei  = (const int*)d_in[1];
    const int*   bat = (const int*)d_in[2];
    const float* W1  = (const float*)d_in[3];
    const float* b1  = (const float*)d_in[4];
    const float* W2  = (const float*)d_in[5];
    const float* b2  = (const float*)d_in[6];
    const float* W3  = (const float*)d_in[7];
    const float* b3  = (const float*)d_in[8];
    const float* Wf  = (const float*)d_in[9];
    const float* bf  = (const float*)d_in[10];
    const float* Wp  = (const float*)d_in[11];
    const float* bp  = (const float*)d_in[12];
    float* out = (float*)d_out;

    char* w = (char*)d_ws;
    unsigned short* xb  = (unsigned short*)w;  w += (size_t)NN * DD * 2;   // bf16 x
    unsigned short* mb  = (unsigned short*)w;  w += (size_t)NN * HH * 2;   // bf16 gemm out
    unsigned short* hb  = (unsigned short*)w;  w += (size_t)NN * HH * 2;   // bf16 h (layer in)
    unsigned short* hb2 = (unsigned short*)w;  w += (size_t)NN * HH * 2;   // bf16 h (layer out)
    unsigned short* W1t = (unsigned short*)w;  w += (size_t)DD * HH * 2;
    unsigned short* W2t = (unsigned short*)w;  w += (size_t)HH * HH * 2;
    unsigned short* W3t = (unsigned short*)w;  w += (size_t)HH * HH * 2;
    float* dinv   = (float*)w;                 w += (size_t)NN * 4;
    int*   degc   = (int*)w;                   w += (size_t)NN * 4;
    int*   rp     = (int*)w;                   w += (size_t)(NN + 4) * 4;
    int*   cur    = (int*)w;                   w += (size_t)NN * 4;
    uint2* er     = (uint2*)w;                 w += (size_t)EE * 8;
    int*   bsum   = (int*)w;                   w += 64 * 4;
    int*   boff   = (int*)w;                   w += 64 * 4;
    float* pooled = (float*)w;                 w += (size_t)GG * HH * 4;
    float* cnts   = (float*)w;                 w += (size_t)GG * 4;

    hipMemsetAsync(degc, 0, (size_t)NN * 4, stream);
    hipMemsetAsync(pooled, 0, (size_t)(GG * HH + GG) * 4, stream);

    // graph structure
    k_count<<<(EE + 255) / 256, 256, 0, stream>>>(ei, degc);
    int nb = (NN + 1023) / 1024;
    k_scan1<<<nb, 1024, 0, stream>>>(degc, rp, bsum);
    k_scan2<<<1, 64, 0, stream>>>(bsum, boff, nb, rp + NN);
    k_scan3<<<(NN + 255) / 256, 256, 0, stream>>>(rp, boff, cur, degc, dinv);
    k_fill<<<(EE + 255) / 256, 256, 0, stream>>>(ei, cur, dinv, er);

    // conversions
    k_cvt_x<<<(NN * DD / 4 + 255) / 256, 256, 0, stream>>>(x, xb, NN * DD / 4);
    k_cvt_wall<<<(262144 + 255) / 256, 256, 0, stream>>>(W1, W2, W3, W1t, W2t, W3t);

    dim3 gg((NN + 127) / 128, 2);
    // layer 1
    k_gemm_bf16<<<gg, 256, 0, stream>>>(xb, W1t, mb, NN, DD);
    k_agg<<<(NN + 3) / 4, 256, 0, stream>>>(mb, b1, dinv, rp, er, hb, 1);
    // layer 2
    k_gemm_bf16<<<gg, 256, 0, stream>>>(hb, W2t, mb, NN, HH);
    k_agg<<<(NN + 3) / 4, 256, 0, stream>>>(mb, b2, dinv, rp, er, hb2, 1);
    // layer 3
    k_gemm_bf16<<<gg, 256, 0, stream>>>(hb2, W3t, mb, NN, HH);
    k_agg<<<(NN + 3) / 4, 256, 0, stream>>>(mb, b3, dinv, rp, er, hb, 0);

    k_pool<<<256, 256, 0, stream>>>(hb, bat, pooled, cnts);
    k_head<<<1, 1024, 0, stream>>>(pooled, cnts, Wf, bf, Wp, bp, out);
}